// Round 3
// baseline (365.435 us; speedup 1.0000x reference)
//
#include <hip/hip_runtime.h>
#include <hip/hip_bf16.h>

using bf16 = __hip_bfloat16;
typedef __attribute__((ext_vector_type(8))) short bf16x8;
typedef __attribute__((ext_vector_type(4))) float f32x4;
typedef __attribute__((ext_vector_type(16))) float f32x16;
typedef __attribute__((ext_vector_type(4))) unsigned int u32x4;

constexpr int Bz  = 2;
constexpr int SEQ = 2048;
constexpr int DM  = 2048;
constexpr int H   = 16;
constexpr int HD  = 128;
constexpr long MROWS = (long)Bz * SEQ;   // 4096
constexpr int EQ  = 3 * DM;              // 6144
// 1/sqrt(128) * log2(e): fold softmax base-2 conversion into Q scaling
constexpr float QSCALE_L2E = 0.12751743427795914f;

__device__ __forceinline__ float bf2f(bf16 x) { return __bfloat162float(x); }
__device__ __forceinline__ bf16  f2bf(float x) { return __float2bfloat16(x); }

__device__ __forceinline__ float fexp2(float x) {
  float r;
  asm("v_exp_f32 %0, %1" : "=v"(r) : "v"(x));
  return r;
}

__device__ __forceinline__ void gl_lds16(const void* g, void* l) {
  __builtin_amdgcn_global_load_lds(
      (const __attribute__((address_space(1))) unsigned int*)g,
      (__attribute__((address_space(3))) unsigned int*)l, 16, 0, 0);
}

// ---------------- fp32 -> bf16 convert (vectorized) ----------------
__global__ void f32_to_bf16(const float* __restrict__ in, bf16* __restrict__ out, long n) {
  long i = ((long)blockIdx.x * blockDim.x + threadIdx.x) * 4;
  if (i >= n) return;
  float4 v = *(const float4*)(in + i);
  bf16 tmp[4] = {f2bf(v.x), f2bf(v.y), f2bf(v.z), f2bf(v.w)};
  *(uint2*)(out + i) = *(uint2*)tmp;
}

// ---------------- RoPE table ----------------
__global__ void rope_table(float* __restrict__ ct, float* __restrict__ st) {
  int idx = blockIdx.x * 256 + threadIdx.x;
  if (idx >= SEQ * 64) return;
  int j = idx & 63, n = idx >> 6;
  double inv = exp(-(double)j / 64.0 * 9.210340371976184); // 10000^{-j/64}
  double a = (double)n * inv;
  ct[idx] = (float)cos(a);
  st[idx] = (float)sin(a);
}

// ============== 256x256 8-phase GEMM: C[M,N] = A[M,K] * B[N,K]^T (+bias) ==============
// 8 waves (2M x 4N), per-wave 128x64 via interleaved frag mapping g=wm+2i, gN=wn+4j.
// BK=64 double-buffered, 4 phases/K-tile, counted vmcnt(4) (never 0 in loop),
// T2 slot-XOR swizzle (pre-swizzled global source, swizzled ds_read).
template <int KTOT, int OUT_BF16>
__global__ __launch_bounds__(512, 2) void gemm256(const bf16* __restrict__ A,
                                                  const bf16* __restrict__ Bm,
                                                  void* __restrict__ Cv,
                                                  const float* __restrict__ bias,
                                                  int M, int Nn) {
  constexpr int NT = KTOT / 64;
  __shared__ alignas(16) bf16 lsA[2][256 * 64];  // 64 KiB
  __shared__ alignas(16) bf16 lsB[2][256 * 64];  // 64 KiB

  // bijective XCD swizzle (nwg % 8 == 0 for all our grids)
  const int nwg = gridDim.x;
  const int f = blockIdx.x;
  const int wg = (f & 7) * (nwg >> 3) + (f >> 3);
  const int nbm = M >> 8;
  const long am0 = (long)(wg % nbm) * 256;
  const long bn0 = (long)(wg / nbm) * 256;

  const int tid = threadIdx.x;
  const int wv = tid >> 6, ln = tid & 63;
  const int wm = wv & 1, wn = wv >> 1;      // 2 x 4 wave grid
  const int fr = ln & 15, kq = ln >> 4;
  const int sr8 = ln >> 3;                  // staging: row within 8-row slab
  const int ss  = ln & 7;                   // staging: physical 16B slot

  f32x4 acc[8][4] = {};

  // p: 0 = A half0, 1 = B half0, 2 = B half1, 3 = A half1
  auto stage_chunk = [&](int buf, int t, int p) {
    const bool isA = (p == 0) || (p == 3);
    const int half = (p >= 2) ? 1 : 0;
    const long rowbase = isA ? am0 : bn0;
    const bf16* g = isA ? A : Bm;
    bf16* lb = isA ? &lsA[buf][0] : &lsB[buf][0];
    const int kt = t * 64;
#pragma unroll
    for (int ld = 0; ld < 2; ++ld) {
      const int r = half * 128 + ld * 64 + wv * 8 + sr8;   // 0..255
      const int sl = ss ^ (r & 7);                          // pre-swizzled source slot
      const bf16* src = g + (rowbase + r) * KTOT + kt + sl * 8;
      gl_lds16(src, lb + (half * 128 + ld * 64 + wv * 8) * 64);
    }
  };

  auto lda = [&](int buf, int g, int ks) {
    const int row = g * 16 + fr;
    const int sl = (ks * 4 + kq) ^ (row & 7);
    return *(const bf16x8*)((const char*)&lsA[buf][0] + row * 128 + sl * 16);
  };
  auto ldb = [&](int buf, int g, int ks) {
    const int row = g * 16 + fr;
    const int sl = (ks * 4 + kq) ^ (row & 7);
    return *(const bf16x8*)((const char*)&lsB[buf][0] + row * 128 + sl * 16);
  };

  // prologue: tile 0, all 4 chunks, full drain
#pragma unroll
  for (int p = 0; p < 4; ++p) stage_chunk(0, 0, p);
  asm volatile("s_waitcnt vmcnt(0)" ::: "memory");
  __builtin_amdgcn_s_barrier();

#pragma unroll 2
  for (int t = 0; t < NT; ++t) {
    const int cur = t & 1;
#pragma unroll
    for (int p = 0; p < 4; ++p) {
      const int ih = p >> 1, jh = p & 1;   // quadrant: A-half ih, B-half jh
      bf16x8 af[4][2], bq[2][2];
#pragma unroll
      for (int i2 = 0; i2 < 4; ++i2)
#pragma unroll
        for (int ks = 0; ks < 2; ++ks)
          af[i2][ks] = lda(cur, wm + 2 * (ih * 4 + i2), ks);
#pragma unroll
      for (int j2 = 0; j2 < 2; ++j2)
#pragma unroll
        for (int ks = 0; ks < 2; ++ks)
          bq[j2][ks] = ldb(cur, wn + 4 * (jh * 2 + j2), ks);

      if (t + 1 < NT) {
        stage_chunk(cur ^ 1, t + 1, p);
        asm volatile("s_waitcnt vmcnt(4)" ::: "memory");
      } else if (p == 0) {
        asm volatile("s_waitcnt vmcnt(2)" ::: "memory");
      } else if (p == 1) {
        asm volatile("s_waitcnt vmcnt(0)" ::: "memory");
      }
      __builtin_amdgcn_s_barrier();

      __builtin_amdgcn_s_setprio(1);
#pragma unroll
      for (int i2 = 0; i2 < 4; ++i2)
#pragma unroll
        for (int j2 = 0; j2 < 2; ++j2)
#pragma unroll
          for (int ks = 0; ks < 2; ++ks)
            acc[ih * 4 + i2][jh * 2 + j2] = __builtin_amdgcn_mfma_f32_16x16x32_bf16(
                af[i2][ks], bq[j2][ks], acc[ih * 4 + i2][jh * 2 + j2], 0, 0, 0);
      __builtin_amdgcn_s_setprio(0);
      __builtin_amdgcn_s_barrier();
    }
  }

  // epilogue
#pragma unroll
  for (int i = 0; i < 8; ++i) {
    const long row0 = am0 + (wm + 2 * i) * 16 + kq * 4;
#pragma unroll
    for (int j = 0; j < 4; ++j) {
      const long col = bn0 + (wn + 4 * j) * 16 + fr;
      const float bv = bias ? bias[col] : 0.f;
#pragma unroll
      for (int q = 0; q < 4; ++q) {
        const float v = acc[i][j][q] + bv;
        if (OUT_BF16) ((bf16*)Cv)[(row0 + q) * Nn + col] = f2bf(v);
        else          ((float*)Cv)[(row0 + q) * Nn + col] = v;
      }
    }
  }
}

// ---------------- RoPE + head reshape ----------------
__global__ void rope_reshape(const bf16* __restrict__ qkv, const float* __restrict__ ct,
                             const float* __restrict__ st, bf16* __restrict__ q_r,
                             bf16* __restrict__ k_r) {
  long idx = (long)blockIdx.x * 256 + threadIdx.x;
  int j = idx & 63;
  int h = (idx >> 6) & 15;
  int n = (idx >> 10) & 2047;
  int b = (int)(idx >> 21);
  long row = (long)b * SEQ + n;
  float c = ct[n * 64 + j], s = st[n * 64 + j];
  long qoff = row * EQ + h * 128 + j;
  float q1 = bf2f(qkv[qoff]),        q2 = bf2f(qkv[qoff + 64]);
  float k1 = bf2f(qkv[qoff + 2048]), k2 = bf2f(qkv[qoff + 2048 + 64]);
  long obase = ((long)(b * 16 + h) * SEQ + n) * HD + j;
  q_r[obase]      = f2bf((q1 * c - q2 * s) * QSCALE_L2E);
  q_r[obase + 64] = f2bf((q1 * s + q2 * c) * QSCALE_L2E);
  k_r[obase]      = f2bf(k1 * c - k2 * s);
  k_r[obase + 64] = f2bf(k1 * s + k2 * c);
}

// ---------------- V transpose: qkv v-part -> v_t [bh, d(128), n(2048)] ----------------
__global__ __launch_bounds__(256) void v_transpose(const bf16* __restrict__ qkv,
                                                   bf16* __restrict__ v_t) {
  __shared__ bf16 tile[64][65];
  int bh = blockIdx.z;
  int b = bh >> 4, h = bh & 15;
  int n0 = blockIdx.y * 64, d0 = blockIdx.x * 64;
  int t = threadIdx.x;
#pragma unroll
  for (int p = 0; p < 16; ++p) {
    int e = p * 256 + t;
    int dn = e & 63, nn = e >> 6;
    tile[nn][dn] = qkv[(long)(b * SEQ + n0 + nn) * EQ + 2 * DM + h * 128 + d0 + dn];
  }
  __syncthreads();
#pragma unroll
  for (int p = 0; p < 16; ++p) {
    int e = p * 256 + t;
    int nn = e & 63, dd = e >> 6;
    v_t[((long)bh * HD + d0 + dd) * SEQ + n0 + nn] = tile[nn][dd];
  }
}

// ---------------- Flash attention, swapped-QK^T 32x32 structure ----------------
__global__ __launch_bounds__(256, 2) void attn_fwd(const bf16* __restrict__ q_r,
                                                   const bf16* __restrict__ k_r,
                                                   const bf16* __restrict__ v_t,
                                                   bf16* __restrict__ ao) {
  __shared__ alignas(16) char lds[65536];

  const int flat = blockIdx.y * gridDim.x + blockIdx.x;   // 0..511
  const int bh = (flat & 7) * 4 + ((flat >> 3) >> 4);
  const int qt = (flat >> 3) & 15;
  const int b = bh >> 4, h = bh & 15;

  const int wv = threadIdx.x >> 6, ln = threadIdx.x & 63;
  const int lh = ln >> 5;
  const int lq = ln & 31;
  const int q0 = qt * 128 + wv * 32;

  bf16x8 aq[8];
  {
    const char* qbase = (const char*)(q_r + ((long)bh * SEQ + q0 + lq) * HD);
#pragma unroll
    for (int ks = 0; ks < 8; ++ks)
      aq[ks] = *(const bf16x8*)(qbase + ks * 32 + lh * 16);
  }

  f32x16 oacc[4] = {};
  float mrow = -1e30f, lsum = 0.f;

  auto stage = [&](int buf, int t) {
    char* kb = lds + buf * 16384;
    char* vb = lds + 32768 + buf * 16384;
#pragma unroll
    for (int cc = 0; cc < 8; ++cc) {
      const int chunk = wv * 8 + cc;
      if (chunk < 16) {
        const int r = chunk * 4 + (ln >> 4);
        const char* src = (const char*)k_r + ((long)bh * SEQ + t * 64 + r) * 256 +
                          (((ln & 15) ^ (r & 15)) << 4);
        gl_lds16(src, kb + chunk * 1024);
      } else {
        const int c2 = chunk - 16;
        const int r = c2 * 8 + (ln >> 3);
        const char* src = (const char*)v_t + ((long)bh * HD + r) * (SEQ * 2) + t * 128 +
                          (((ln & 7) ^ (r & 7)) << 4);
        gl_lds16(src, vb + c2 * 1024);
      }
    }
  };

  stage(0, 0);
  __syncthreads();

  for (int t = 0; t < SEQ / 64; ++t) {
    const int cur = t & 1;
    if (t + 1 < SEQ / 64) stage(cur ^ 1, t + 1);
    const char* kb = lds + cur * 16384;
    const char* vb = lds + 32768 + cur * 16384;

    f32x16 sacc[2] = {};
    __builtin_amdgcn_s_setprio(1);
#pragma unroll
    for (int kvs = 0; kvs < 2; ++kvs) {
      const int kv = kvs * 32 + lq;
#pragma unroll
      for (int ks = 0; ks < 8; ++ks) {
        bf16x8 kf = *(const bf16x8*)(kb + kv * 256 + ((((ks << 1) | lh) ^ (kv & 15)) << 4));
        sacc[kvs] = __builtin_amdgcn_mfma_f32_32x32x16_bf16(kf, aq[ks], sacc[kvs], 0, 0, 0);
      }
    }
    __builtin_amdgcn_s_setprio(0);

    float mx = sacc[0][0];
#pragma unroll
    for (int r = 1; r < 16; ++r) mx = fmaxf(mx, sacc[0][r]);
#pragma unroll
    for (int r = 0; r < 16; ++r) mx = fmaxf(mx, sacc[1][r]);
    mx = fmaxf(mx, __shfl_xor(mx, 32, 64));
    const float mn = fmaxf(mrow, mx);
    const float scale = fexp2(mrow - mn);
    mrow = mn;
    float psum = 0.f;
#pragma unroll
    for (int k2 = 0; k2 < 2; ++k2)
#pragma unroll
      for (int r = 0; r < 16; ++r) {
        const float pv = fexp2(sacc[k2][r] - mn);
        sacc[k2][r] = pv;
        psum += pv;
      }
    psum += __shfl_xor(psum, 32, 64);
    lsum = lsum * scale + psum;
#pragma unroll
    for (int dt = 0; dt < 4; ++dt) oacc[dt] *= scale;

    bf16x8 pfrag[4];
#pragma unroll
    for (int k2 = 0; k2 < 2; ++k2) {
      unsigned int pk[8];
#pragma unroll
      for (int i = 0; i < 8; ++i) {
        unsigned int lo = __bfloat16_as_ushort(f2bf(sacc[k2][2 * i]));
        unsigned int hi = __bfloat16_as_ushort(f2bf(sacc[k2][2 * i + 1]));
        pk[i] = lo | (hi << 16);
      }
#pragma unroll
      for (int fb = 0; fb < 2; ++fb) {
        const unsigned int a0 = pk[fb * 4 + 0], a1 = pk[fb * 4 + 1];
        const unsigned int b0 = pk[fb * 4 + 2], b1 = pk[fb * 4 + 3];
        const unsigned int sb0 = __shfl_xor(b0, 32, 64);
        const unsigned int sb1 = __shfl_xor(b1, 32, 64);
        const unsigned int sa0 = __shfl_xor(a0, 32, 64);
        const unsigned int sa1 = __shfl_xor(a1, 32, 64);
        u32x4 wvec;
        wvec.x = lh ? sb0 : a0;
        wvec.y = lh ? sb1 : a1;
        wvec.z = lh ? b0 : sa0;
        wvec.w = lh ? b1 : sa1;
        pfrag[k2 * 2 + fb] = __builtin_bit_cast(bf16x8, wvec);
      }
    }

    __builtin_amdgcn_s_setprio(1);
#pragma unroll
    for (int dt = 0; dt < 4; ++dt) {
      const int d = dt * 32 + lq;
#pragma unroll
      for (int kk = 0; kk < 4; ++kk) {
        bf16x8 vf = *(const bf16x8*)(vb + d * 128 + ((((kk << 1) | lh) ^ (d & 7)) << 4));
        oacc[dt] = __builtin_amdgcn_mfma_f32_32x32x16_bf16(vf, pfrag[kk], oacc[dt], 0, 0, 0);
      }
    }
    __builtin_amdgcn_s_setprio(0);
    __syncthreads();
  }

  const float inv = 1.0f / lsum;
  bf16* ob = (bf16*)lds;
  const int qloc = wv * 32 + lq;
#pragma unroll
  for (int dt = 0; dt < 4; ++dt)
#pragma unroll
    for (int r = 0; r < 16; ++r) {
      const int d = dt * 32 + (r & 3) + 8 * (r >> 2) + 4 * lh;
      ob[qloc * 132 + d] = f2bf(oacc[dt][r] * inv);
    }
#pragma unroll
  for (int it = 0; it < 8; ++it) {
    const int c = it * 64 + ln;
    const int qq = c >> 4, dc = c & 15;
    const char* srcp = (const char*)ob + (wv * 32 + qq) * 264 + dc * 16;
    uint2 v0 = *(const uint2*)srcp;
    uint2 v1 = *(const uint2*)(srcp + 8);
    uint4 outv;
    outv.x = v0.x; outv.y = v0.y; outv.z = v1.x; outv.w = v1.y;
    *(uint4*)((char*)(ao + ((long)b * SEQ + qt * 128 + wv * 32 + qq) * DM + h * 128) + dc * 16) = outv;
  }
}

// ---------------- launch ----------------
extern "C" void kernel_launch(void* const* d_in, const int* in_sizes, int n_in,
                              void* d_out, int out_size, void* d_ws, size_t ws_size,
                              hipStream_t stream) {
  const float* x      = (const float*)d_in[0];
  const float* w_qkv  = (const float*)d_in[1];
  const float* w_proj = (const float*)d_in[2];
  const float* b_proj = (const float*)d_in[3];

  char* ws = (char*)d_ws;
  size_t off = 0;
  auto alloc = [&](size_t bytes) {
    void* p = ws + off;
    off += (bytes + 255) & ~(size_t)255;
    return p;
  };
  bf16* xb     = (bf16*)alloc((size_t)MROWS * DM * 2);
  bf16* wqkvb  = (bf16*)alloc((size_t)EQ * DM * 2);
  bf16* wprojb = (bf16*)alloc((size_t)DM * DM * 2);
  bf16* qkvb   = (bf16*)alloc((size_t)MROWS * EQ * 2);
  bf16* q_r    = (bf16*)alloc((size_t)Bz * H * SEQ * HD * 2);
  bf16* k_r    = (bf16*)alloc((size_t)Bz * H * SEQ * HD * 2);
  bf16* v_t    = (bf16*)alloc((size_t)Bz * H * SEQ * HD * 2);
  bf16* aob    = (bf16*)alloc((size_t)MROWS * DM * 2);
  float* ct    = (float*)alloc((size_t)SEQ * 64 * 4);
  float* st    = (float*)alloc((size_t)SEQ * 64 * 4);

  {
    long n = MROWS * DM;
    f32_to_bf16<<<(int)((n / 4 + 255) / 256), 256, 0, stream>>>(x, xb, n);
  }
  {
    long n = (long)EQ * DM;
    f32_to_bf16<<<(int)((n / 4 + 255) / 256), 256, 0, stream>>>(w_qkv, wqkvb, n);
  }
  {
    long n = (long)DM * DM;
    f32_to_bf16<<<(int)((n / 4 + 255) / 256), 256, 0, stream>>>(w_proj, wprojb, n);
  }
  rope_table<<<(SEQ * 64) / 256, 256, 0, stream>>>(ct, st);

  gemm256<2048, 1><<<(EQ / 256) * (int)(MROWS / 256), 512, 0, stream>>>(
      xb, wqkvb, qkvb, nullptr, (int)MROWS, EQ);

  rope_reshape<<<(int)((long)Bz * SEQ * H * 64 / 256), 256, 0, stream>>>(qkvb, ct, st, q_r, k_r);
  v_transpose<<<dim3(HD / 64, SEQ / 64, Bz * H), 256, 0, stream>>>(qkvb, v_t);

  attn_fwd<<<dim3(16, Bz * H), 256, 0, stream>>>(q_r, k_r, v_t, aob);

  gemm256<2048, 0><<<(DM / 256) * (int)(MROWS / 256), 512, 0, stream>>>(
      aob, wprojb, d_out, b_proj, (int)MROWS, DM);
}

// Round 4
// 312.818 us; speedup vs baseline: 1.1682x; 1.1682x over previous
//
#include <hip/hip_runtime.h>
#include <hip/hip_bf16.h>

using bf16 = __hip_bfloat16;
typedef __attribute__((ext_vector_type(8))) short bf16x8;
typedef __attribute__((ext_vector_type(4))) float f32x4;
typedef __attribute__((ext_vector_type(16))) float f32x16;
typedef __attribute__((ext_vector_type(4))) unsigned int u32x4;

constexpr int Bz  = 2;
constexpr int SEQ = 2048;
constexpr int DM  = 2048;
constexpr int H   = 16;
constexpr int HD  = 128;
constexpr long MROWS = (long)Bz * SEQ;   // 4096
constexpr int EQ  = 3 * DM;              // 6144
// 1/sqrt(128) * log2(e): fold softmax base-2 conversion into Q scaling
constexpr float QSCALE_L2E = 0.12751743427795914f;

__device__ __forceinline__ float bf2f(bf16 x) { return __bfloat162float(x); }
__device__ __forceinline__ bf16  f2bf(float x) { return __float2bfloat16(x); }

__device__ __forceinline__ float fexp2(float x) {
  float r;
  asm("v_exp_f32 %0, %1" : "=v"(r) : "v"(x));
  return r;
}

__device__ __forceinline__ void gl_lds16(const void* g, void* l) {
  __builtin_amdgcn_global_load_lds(
      (const __attribute__((address_space(1))) unsigned int*)g,
      (__attribute__((address_space(3))) unsigned int*)l, 16, 0, 0);
}

// ---------------- fp32 -> bf16 convert (vectorized) ----------------
__global__ void f32_to_bf16(const float* __restrict__ in, bf16* __restrict__ out, long n) {
  long i = ((long)blockIdx.x * blockDim.x + threadIdx.x) * 4;
  if (i >= n) return;
  float4 v = *(const float4*)(in + i);
  bf16 tmp[4] = {f2bf(v.x), f2bf(v.y), f2bf(v.z), f2bf(v.w)};
  *(uint2*)(out + i) = *(uint2*)tmp;
}

// ---------------- RoPE table ----------------
__global__ void rope_table(float* __restrict__ ct, float* __restrict__ st) {
  int idx = blockIdx.x * 256 + threadIdx.x;
  if (idx >= SEQ * 64) return;
  int j = idx & 63, n = idx >> 6;
  double inv = exp(-(double)j / 64.0 * 9.210340371976184); // 10000^{-j/64}
  double a = (double)n * inv;
  ct[idx] = (float)cos(a);
  st[idx] = (float)sin(a);
}

// ============== 256x256 8-phase GEMM: C[M,N] = A[M,K] * B[N,K]^T (+bias) ==============
// 8 waves (2M x 4N), per-wave 128x64 via interleaved frag mapping g=wm+2i, gN=wn+4j.
// BK=64 double-buffered. Frag-persistent phases (each frag ds_read ONCE per K-tile):
//   P0: read A(i0-3)+B(j0,1), mfma quad(0,0); P1: read B(j2,3), mfma(0,1);
//   P2: read A(i4-7), mfma(1,0);              P3: no reads,    mfma(1,1).
// One barrier/phase; counted vmcnt(4) (never 0 in loop); T2 slot-XOR swizzle.
template <int KTOT, int OUT_BF16>
__global__ __launch_bounds__(512, 2) void gemm256(const bf16* __restrict__ A,
                                                  const bf16* __restrict__ Bm,
                                                  void* __restrict__ Cv,
                                                  const float* __restrict__ bias,
                                                  int M, int Nn) {
  constexpr int NT = KTOT / 64;
  __shared__ alignas(16) bf16 lsA[2][256 * 64];  // 64 KiB
  __shared__ alignas(16) bf16 lsB[2][256 * 64];  // 64 KiB

  // bijective XCD swizzle (nwg % 8 == 0 for all our grids)
  const int nwg = gridDim.x;
  const int f = blockIdx.x;
  const int wg = (f & 7) * (nwg >> 3) + (f >> 3);
  const int nbm = M >> 8;
  const long am0 = (long)(wg % nbm) * 256;
  const long bn0 = (long)(wg / nbm) * 256;

  const int tid = threadIdx.x;
  const int wv = tid >> 6, ln = tid & 63;
  const int wm = wv & 1, wn = wv >> 1;      // 2 x 4 wave grid
  const int fr = ln & 15, kq = ln >> 4;
  const int sr8 = ln >> 3;                  // staging: row within 8-row slab
  const int ss  = ln & 7;                   // staging: physical 16B slot

  f32x4 acc[8][4] = {};
  bf16x8 af[8];   // current A half: 4 i-frags x 2 ks
  bf16x8 bq[8];   // all B frags: 4 j-frags x 2 ks (persist whole K-tile)

  // p: 0 = A half0, 1 = B half0, 2 = B half1, 3 = A half1
  auto stage_chunk = [&](int buf, int t, int p) {
    const bool isA = (p == 0) || (p == 3);
    const int half = (p >= 2) ? 1 : 0;
    const long rowbase = isA ? am0 : bn0;
    const bf16* g = isA ? A : Bm;
    bf16* lb = isA ? &lsA[buf][0] : &lsB[buf][0];
    const int kt = t * 64;
#pragma unroll
    for (int ld = 0; ld < 2; ++ld) {
      const int r = half * 128 + ld * 64 + wv * 8 + sr8;   // 0..255
      const int sl = ss ^ (r & 7);                          // pre-swizzled source slot
      const bf16* src = g + (rowbase + r) * KTOT + kt + sl * 8;
      gl_lds16(src, lb + (half * 128 + ld * 64 + wv * 8) * 64);
    }
  };

  auto lda = [&](int buf, int g, int ks) {
    const int row = g * 16 + fr;
    const int sl = (ks * 4 + kq) ^ (row & 7);
    return *(const bf16x8*)((const char*)&lsA[buf][0] + row * 128 + sl * 16);
  };
  auto ldb = [&](int buf, int g, int ks) {
    const int row = g * 16 + fr;
    const int sl = (ks * 4 + kq) ^ (row & 7);
    return *(const bf16x8*)((const char*)&lsB[buf][0] + row * 128 + sl * 16);
  };

  // prologue: tile 0, all 4 chunks, full drain
#pragma unroll
  for (int p = 0; p < 4; ++p) stage_chunk(0, 0, p);
  asm volatile("s_waitcnt vmcnt(0)" ::: "memory");
  __builtin_amdgcn_s_barrier();

#pragma unroll 2
  for (int t = 0; t < NT; ++t) {
    const int cur = t & 1;
    const bool pre = (t + 1 < NT);

    // ---- phase 0: read A i0..3 + B j0..1; mfma quad (A-half0, B-half0)
#pragma unroll
    for (int i = 0; i < 4; ++i)
#pragma unroll
      for (int ks = 0; ks < 2; ++ks)
        af[i * 2 + ks] = lda(cur, wm + 2 * i, ks);
#pragma unroll
    for (int j = 0; j < 2; ++j)
#pragma unroll
      for (int ks = 0; ks < 2; ++ks)
        bq[j * 2 + ks] = ldb(cur, wn + 4 * j, ks);
    if (pre) {
      stage_chunk(cur ^ 1, t + 1, 0);
      asm volatile("s_waitcnt vmcnt(4)" ::: "memory");
    } else {
      asm volatile("s_waitcnt vmcnt(2)" ::: "memory");
    }
    __builtin_amdgcn_s_barrier();
    __builtin_amdgcn_s_setprio(1);
#pragma unroll
    for (int i = 0; i < 4; ++i)
#pragma unroll
      for (int j = 0; j < 2; ++j)
#pragma unroll
        for (int ks = 0; ks < 2; ++ks)
          acc[i][j] = __builtin_amdgcn_mfma_f32_16x16x32_bf16(af[i * 2 + ks], bq[j * 2 + ks],
                                                              acc[i][j], 0, 0, 0);
    __builtin_amdgcn_s_setprio(0);

    // ---- phase 1: read B j2..3; mfma quad (A-half0, B-half1)
#pragma unroll
    for (int j = 0; j < 2; ++j)
#pragma unroll
      for (int ks = 0; ks < 2; ++ks)
        bq[4 + j * 2 + ks] = ldb(cur, wn + 4 * (2 + j), ks);
    if (pre) {
      stage_chunk(cur ^ 1, t + 1, 1);
      asm volatile("s_waitcnt vmcnt(4)" ::: "memory");
    } else {
      asm volatile("s_waitcnt vmcnt(0)" ::: "memory");
    }
    __builtin_amdgcn_s_barrier();
    __builtin_amdgcn_s_setprio(1);
#pragma unroll
    for (int i = 0; i < 4; ++i)
#pragma unroll
      for (int j = 0; j < 2; ++j)
#pragma unroll
        for (int ks = 0; ks < 2; ++ks)
          acc[i][2 + j] = __builtin_amdgcn_mfma_f32_16x16x32_bf16(af[i * 2 + ks], bq[4 + j * 2 + ks],
                                                                  acc[i][2 + j], 0, 0, 0);
    __builtin_amdgcn_s_setprio(0);

    // ---- phase 2: read A i4..7; mfma quad (A-half1, B-half0)
#pragma unroll
    for (int i = 0; i < 4; ++i)
#pragma unroll
      for (int ks = 0; ks < 2; ++ks)
        af[i * 2 + ks] = lda(cur, wm + 2 * (4 + i), ks);
    if (pre) {
      stage_chunk(cur ^ 1, t + 1, 2);
      asm volatile("s_waitcnt vmcnt(4)" ::: "memory");
    }
    __builtin_amdgcn_s_barrier();
    __builtin_amdgcn_s_setprio(1);
#pragma unroll
    for (int i = 0; i < 4; ++i)
#pragma unroll
      for (int j = 0; j < 2; ++j)
#pragma unroll
        for (int ks = 0; ks < 2; ++ks)
          acc[4 + i][j] = __builtin_amdgcn_mfma_f32_16x16x32_bf16(af[i * 2 + ks], bq[j * 2 + ks],
                                                                  acc[4 + i][j], 0, 0, 0);
    __builtin_amdgcn_s_setprio(0);

    // ---- phase 3: no reads; mfma quad (A-half1, B-half1)
    if (pre) {
      stage_chunk(cur ^ 1, t + 1, 3);
      asm volatile("s_waitcnt vmcnt(4)" ::: "memory");
    }
    __builtin_amdgcn_s_barrier();
    __builtin_amdgcn_s_setprio(1);
#pragma unroll
    for (int i = 0; i < 4; ++i)
#pragma unroll
      for (int j = 0; j < 2; ++j)
#pragma unroll
        for (int ks = 0; ks < 2; ++ks)
          acc[4 + i][2 + j] = __builtin_amdgcn_mfma_f32_16x16x32_bf16(
              af[i * 2 + ks], bq[4 + j * 2 + ks], acc[4 + i][2 + j], 0, 0, 0);
    __builtin_amdgcn_s_setprio(0);
  }

  // epilogue
#pragma unroll
  for (int i = 0; i < 8; ++i) {
    const long row0 = am0 + (wm + 2 * i) * 16 + kq * 4;
#pragma unroll
    for (int j = 0; j < 4; ++j) {
      const long col = bn0 + (wn + 4 * j) * 16 + fr;
      const float bv = bias ? bias[col] : 0.f;
#pragma unroll
      for (int q = 0; q < 4; ++q) {
        const float v = acc[i][j][q] + bv;
        if (OUT_BF16) ((bf16*)Cv)[(row0 + q) * Nn + col] = f2bf(v);
        else          ((float*)Cv)[(row0 + q) * Nn + col] = v;
      }
    }
  }
}

// ---------------- RoPE + head reshape ----------------
__global__ void rope_reshape(const bf16* __restrict__ qkv, const float* __restrict__ ct,
                             const float* __restrict__ st, bf16* __restrict__ q_r,
                             bf16* __restrict__ k_r) {
  long idx = (long)blockIdx.x * 256 + threadIdx.x;
  int j = idx & 63;
  int h = (idx >> 6) & 15;
  int n = (idx >> 10) & 2047;
  int b = (int)(idx >> 21);
  long row = (long)b * SEQ + n;
  float c = ct[n * 64 + j], s = st[n * 64 + j];
  long qoff = row * EQ + h * 128 + j;
  float q1 = bf2f(qkv[qoff]),        q2 = bf2f(qkv[qoff + 64]);
  float k1 = bf2f(qkv[qoff + 2048]), k2 = bf2f(qkv[qoff + 2048 + 64]);
  long obase = ((long)(b * 16 + h) * SEQ + n) * HD + j;
  q_r[obase]      = f2bf((q1 * c - q2 * s) * QSCALE_L2E);
  q_r[obase + 64] = f2bf((q1 * s + q2 * c) * QSCALE_L2E);
  k_r[obase]      = f2bf(k1 * c - k2 * s);
  k_r[obase + 64] = f2bf(k1 * s + k2 * c);
}

// ---------------- V transpose: qkv v-part -> v_t [bh, d(128), n(2048)] ----------------
__global__ __launch_bounds__(256) void v_transpose(const bf16* __restrict__ qkv,
                                                   bf16* __restrict__ v_t) {
  __shared__ bf16 tile[64][65];
  int bh = blockIdx.z;
  int b = bh >> 4, h = bh & 15;
  int n0 = blockIdx.y * 64, d0 = blockIdx.x * 64;
  int t = threadIdx.x;
#pragma unroll
  for (int p = 0; p < 16; ++p) {
    int e = p * 256 + t;
    int dn = e & 63, nn = e >> 6;
    tile[nn][dn] = qkv[(long)(b * SEQ + n0 + nn) * EQ + 2 * DM + h * 128 + d0 + dn];
  }
  __syncthreads();
#pragma unroll
  for (int p = 0; p < 16; ++p) {
    int e = p * 256 + t;
    int nn = e & 63, dd = e >> 6;
    v_t[((long)bh * HD + d0 + dd) * SEQ + n0 + nn] = tile[nn][dd];
  }
}

// ---------------- Flash attention, swapped-QK^T 32x32 structure ----------------
__global__ __launch_bounds__(256, 2) void attn_fwd(const bf16* __restrict__ q_r,
                                                   const bf16* __restrict__ k_r,
                                                   const bf16* __restrict__ v_t,
                                                   bf16* __restrict__ ao) {
  __shared__ alignas(16) char lds[65536];

  const int flat = blockIdx.y * gridDim.x + blockIdx.x;   // 0..511
  const int bh = (flat & 7) * 4 + ((flat >> 3) >> 4);
  const int qt = (flat >> 3) & 15;
  const int b = bh >> 4, h = bh & 15;

  const int wv = threadIdx.x >> 6, ln = threadIdx.x & 63;
  const int lh = ln >> 5;
  const int lq = ln & 31;
  const int q0 = qt * 128 + wv * 32;

  bf16x8 aq[8];
  {
    const char* qbase = (const char*)(q_r + ((long)bh * SEQ + q0 + lq) * HD);
#pragma unroll
    for (int ks = 0; ks < 8; ++ks)
      aq[ks] = *(const bf16x8*)(qbase + ks * 32 + lh * 16);
  }

  f32x16 oacc[4] = {};
  float mrow = -1e30f, lsum = 0.f;

  auto stage = [&](int buf, int t) {
    char* kb = lds + buf * 16384;
    char* vb = lds + 32768 + buf * 16384;
#pragma unroll
    for (int cc = 0; cc < 8; ++cc) {
      const int chunk = wv * 8 + cc;
      if (chunk < 16) {
        const int r = chunk * 4 + (ln >> 4);
        const char* src = (const char*)k_r + ((long)bh * SEQ + t * 64 + r) * 256 +
                          (((ln & 15) ^ (r & 15)) << 4);
        gl_lds16(src, kb + chunk * 1024);
      } else {
        const int c2 = chunk - 16;
        const int r = c2 * 8 + (ln >> 3);
        const char* src = (const char*)v_t + ((long)bh * HD + r) * (SEQ * 2) + t * 128 +
                          (((ln & 7) ^ (r & 7)) << 4);
        gl_lds16(src, vb + c2 * 1024);
      }
    }
  };

  stage(0, 0);
  __syncthreads();

  for (int t = 0; t < SEQ / 64; ++t) {
    const int cur = t & 1;
    if (t + 1 < SEQ / 64) stage(cur ^ 1, t + 1);
    const char* kb = lds + cur * 16384;
    const char* vb = lds + 32768 + cur * 16384;

    f32x16 sacc[2] = {};
    __builtin_amdgcn_s_setprio(1);
#pragma unroll
    for (int kvs = 0; kvs < 2; ++kvs) {
      const int kv = kvs * 32 + lq;
#pragma unroll
      for (int ks = 0; ks < 8; ++ks) {
        bf16x8 kf = *(const bf16x8*)(kb + kv * 256 + ((((ks << 1) | lh) ^ (kv & 15)) << 4));
        sacc[kvs] = __builtin_amdgcn_mfma_f32_32x32x16_bf16(kf, aq[ks], sacc[kvs], 0, 0, 0);
      }
    }
    __builtin_amdgcn_s_setprio(0);

    float mx = sacc[0][0];
#pragma unroll
    for (int r = 1; r < 16; ++r) mx = fmaxf(mx, sacc[0][r]);
#pragma unroll
    for (int r = 0; r < 16; ++r) mx = fmaxf(mx, sacc[1][r]);
    mx = fmaxf(mx, __shfl_xor(mx, 32, 64));
    const float mn = fmaxf(mrow, mx);
    const float scale = fexp2(mrow - mn);
    mrow = mn;
    float psum = 0.f;
#pragma unroll
    for (int k2 = 0; k2 < 2; ++k2)
#pragma unroll
      for (int r = 0; r < 16; ++r) {
        const float pv = fexp2(sacc[k2][r] - mn);
        sacc[k2][r] = pv;
        psum += pv;
      }
    psum += __shfl_xor(psum, 32, 64);
    lsum = lsum * scale + psum;
#pragma unroll
    for (int dt = 0; dt < 4; ++dt) oacc[dt] *= scale;

    bf16x8 pfrag[4];
#pragma unroll
    for (int k2 = 0; k2 < 2; ++k2) {
      unsigned int pk[8];
#pragma unroll
      for (int i = 0; i < 8; ++i) {
        unsigned int lo = __bfloat16_as_ushort(f2bf(sacc[k2][2 * i]));
        unsigned int hi = __bfloat16_as_ushort(f2bf(sacc[k2][2 * i + 1]));
        pk[i] = lo | (hi << 16);
      }
#pragma unroll
      for (int fb = 0; fb < 2; ++fb) {
        const unsigned int a0 = pk[fb * 4 + 0], a1 = pk[fb * 4 + 1];
        const unsigned int b0 = pk[fb * 4 + 2], b1 = pk[fb * 4 + 3];
        const unsigned int sb0 = __shfl_xor(b0, 32, 64);
        const unsigned int sb1 = __shfl_xor(b1, 32, 64);
        const unsigned int sa0 = __shfl_xor(a0, 32, 64);
        const unsigned int sa1 = __shfl_xor(a1, 32, 64);
        u32x4 wvec;
        wvec.x = lh ? sb0 : a0;
        wvec.y = lh ? sb1 : a1;
        wvec.z = lh ? b0 : sa0;
        wvec.w = lh ? b1 : sa1;
        pfrag[k2 * 2 + fb] = __builtin_bit_cast(bf16x8, wvec);
      }
    }

    __builtin_amdgcn_s_setprio(1);
#pragma unroll
    for (int dt = 0; dt < 4; ++dt) {
      const int d = dt * 32 + lq;
#pragma unroll
      for (int kk = 0; kk < 4; ++kk) {
        bf16x8 vf = *(const bf16x8*)(vb + d * 128 + ((((kk << 1) | lh) ^ (d & 7)) << 4));
        oacc[dt] = __builtin_amdgcn_mfma_f32_32x32x16_bf16(vf, pfrag[kk], oacc[dt], 0, 0, 0);
      }
    }
    __builtin_amdgcn_s_setprio(0);
    __syncthreads();
  }

  const float inv = 1.0f / lsum;
  bf16* ob = (bf16*)lds;
  const int qloc = wv * 32 + lq;
#pragma unroll
  for (int dt = 0; dt < 4; ++dt)
#pragma unroll
    for (int r = 0; r < 16; ++r) {
      const int d = dt * 32 + (r & 3) + 8 * (r >> 2) + 4 * lh;
      ob[qloc * 132 + d] = f2bf(oacc[dt][r] * inv);
    }
#pragma unroll
  for (int it = 0; it < 8; ++it) {
    const int c = it * 64 + ln;
    const int qq = c >> 4, dc = c & 15;
    const char* srcp = (const char*)ob + (wv * 32 + qq) * 264 + dc * 16;
    uint2 v0 = *(const uint2*)srcp;
    uint2 v1 = *(const uint2*)(srcp + 8);
    uint4 outv;
    outv.x = v0.x; outv.y = v0.y; outv.z = v1.x; outv.w = v1.y;
    *(uint4*)((char*)(ao + ((long)b * SEQ + qt * 128 + wv * 32 + qq) * DM + h * 128) + dc * 16) = outv;
  }
}

// ---------------- launch ----------------
extern "C" void kernel_launch(void* const* d_in, const int* in_sizes, int n_in,
                              void* d_out, int out_size, void* d_ws, size_t ws_size,
                              hipStream_t stream) {
  const float* x      = (const float*)d_in[0];
  const float* w_qkv  = (const float*)d_in[1];
  const float* w_proj = (const float*)d_in[2];
  const float* b_proj = (const float*)d_in[3];

  char* ws = (char*)d_ws;
  size_t off = 0;
  auto alloc = [&](size_t bytes) {
    void* p = ws + off;
    off += (bytes + 255) & ~(size_t)255;
    return p;
  };
  bf16* xb     = (bf16*)alloc((size_t)MROWS * DM * 2);
  bf16* wqkvb  = (bf16*)alloc((size_t)EQ * DM * 2);
  bf16* wprojb = (bf16*)alloc((size_t)DM * DM * 2);
  bf16* qkvb   = (bf16*)alloc((size_t)MROWS * EQ * 2);
  bf16* q_r    = (bf16*)alloc((size_t)Bz * H * SEQ * HD * 2);
  bf16* k_r    = (bf16*)alloc((size_t)Bz * H * SEQ * HD * 2);
  bf16* v_t    = (bf16*)alloc((size_t)Bz * H * SEQ * HD * 2);
  bf16* aob    = (bf16*)alloc((size_t)MROWS * DM * 2);
  float* ct    = (float*)alloc((size_t)SEQ * 64 * 4);
  float* st    = (float*)alloc((size_t)SEQ * 64 * 4);

  {
    long n = MROWS * DM;
    f32_to_bf16<<<(int)((n / 4 + 255) / 256), 256, 0, stream>>>(x, xb, n);
  }
  {
    long n = (long)EQ * DM;
    f32_to_bf16<<<(int)((n / 4 + 255) / 256), 256, 0, stream>>>(w_qkv, wqkvb, n);
  }
  {
    long n = (long)DM * DM;
    f32_to_bf16<<<(int)((n / 4 + 255) / 256), 256, 0, stream>>>(w_proj, wprojb, n);
  }
  rope_table<<<(SEQ * 64) / 256, 256, 0, stream>>>(ct, st);

  gemm256<2048, 1><<<(EQ / 256) * (int)(MROWS / 256), 512, 0, stream>>>(
      xb, wqkvb, qkvb, nullptr, (int)MROWS, EQ);

  rope_reshape<<<(int)((long)Bz * SEQ * H * 64 / 256), 256, 0, stream>>>(qkvb, ct, st, q_r, k_r);
  v_transpose<<<dim3(HD / 64, SEQ / 64, Bz * H), 256, 0, stream>>>(qkvb, v_t);

  attn_fwd<<<dim3(16, Bz * H), 256, 0, stream>>>(q_r, k_r, v_t, aob);

  gemm256<2048, 0><<<(DM / 256) * (int)(MROWS / 256), 512, 0, stream>>>(
      aob, wprojb, d_out, b_proj, (int)MROWS, DM);
}

// Round 5
// 292.805 us; speedup vs baseline: 1.2480x; 1.0683x over previous
//
#include <hip/hip_runtime.h>
#include <hip/hip_bf16.h>

using bf16 = __hip_bfloat16;
typedef __attribute__((ext_vector_type(8))) short bf16x8;
typedef __attribute__((ext_vector_type(4))) float f32x4;
typedef __attribute__((ext_vector_type(16))) float f32x16;
typedef __attribute__((ext_vector_type(4))) unsigned int u32x4;

constexpr int Bz  = 2;
constexpr int SEQ = 2048;
constexpr int DM  = 2048;
constexpr int H   = 16;
constexpr int HD  = 128;
constexpr long MROWS = (long)Bz * SEQ;   // 4096
constexpr int EQ  = 3 * DM;              // 6144
// 1/sqrt(128) * log2(e): fold softmax base-2 conversion into Q scaling
constexpr float QSCALE_L2E = 0.12751743427795914f;

__device__ __forceinline__ float bf2f(bf16 x) { return __bfloat162float(x); }
__device__ __forceinline__ bf16  f2bf(float x) { return __float2bfloat16(x); }

__device__ __forceinline__ float fexp2(float x) {
  float r;
  asm("v_exp_f32 %0, %1" : "=v"(r) : "v"(x));
  return r;
}

template <int N>
__device__ __forceinline__ void waitvm() {
  asm volatile("s_waitcnt vmcnt(%0)" ::"n"(N) : "memory");
}

__device__ __forceinline__ void gl_lds16(const void* g, void* l) {
  __builtin_amdgcn_global_load_lds(
      (const __attribute__((address_space(1))) unsigned int*)g,
      (__attribute__((address_space(3))) unsigned int*)l, 16, 0, 0);
}

// ---------------- fp32 -> bf16 convert (vectorized) ----------------
__global__ void f32_to_bf16(const float* __restrict__ in, bf16* __restrict__ out, long n) {
  long i = ((long)blockIdx.x * blockDim.x + threadIdx.x) * 4;
  if (i >= n) return;
  float4 v = *(const float4*)(in + i);
  bf16 tmp[4] = {f2bf(v.x), f2bf(v.y), f2bf(v.z), f2bf(v.w)};
  *(uint2*)(out + i) = *(uint2*)tmp;
}

// ---------------- RoPE table ----------------
__global__ void rope_table(float* __restrict__ ct, float* __restrict__ st) {
  int idx = blockIdx.x * 256 + threadIdx.x;
  if (idx >= SEQ * 64) return;
  int j = idx & 63, n = idx >> 6;
  double inv = exp(-(double)j / 64.0 * 9.210340371976184); // 10000^{-j/64}
  double a = (double)n * inv;
  ct[idx] = (float)cos(a);
  st[idx] = (float)sin(a);
}

// ============== BM=128 x BN GEMM: C[M,N] = A[M,K] * B[N,K]^T (+bias) ==============
// 8 waves (2M x 4N), per-wave 64 x (BN/4); NBP = BN/128 phases per K-tile(64).
// Phase bp: {read A(8, bp==0 only) + B-pair(4); stage 1 chunk of tile t+1;
//            counted vmcnt; barrier; 16 MFMA (setprio)}.
// Grids: GEMM1 (BN=384) -> 512 blocks = 2 exact rounds; GEMM2 (BN=256) -> 256 = 1 round.
template <int KTOT, int BN, int NBP, int OUT_BF16>
__global__ __launch_bounds__(512) void gemm128(const bf16* __restrict__ A,
                                               const bf16* __restrict__ Bm,
                                               void* __restrict__ Cv,
                                               const float* __restrict__ bias,
                                               int M, int Nn) {
  constexpr int NT = KTOT / 64;
  __shared__ alignas(16) bf16 lsA[2][128 * 64];
  __shared__ alignas(16) bf16 lsB[2][BN * 64];

  // bijective XCD swizzle (nwg % 8 == 0 for both grids)
  const int nwg = gridDim.x;
  const int f = blockIdx.x;
  const int wg = (f & 7) * (nwg >> 3) + (f >> 3);
  const int nbm = M >> 7;
  const long am0 = (long)(wg % nbm) * 128;
  const long bn0 = (long)(wg / nbm) * BN;

  const int tid = threadIdx.x;
  const int wv = tid >> 6, ln = tid & 63;
  const int wm = wv & 1, wn = wv >> 1;      // 2 x 4 wave grid
  const int fr = ln & 15, kq = ln >> 4;
  const int sr8 = ln >> 3;                  // staging row within 8-row slab
  const int ss  = ln & 7;                   // staging physical 16B slot

  f32x4 acc[4][2 * NBP] = {};
  bf16x8 af[8];   // A frags: 4 i x 2 ks (persist across the K-tile)
  bf16x8 bq[4];   // current B pair: 2 j x 2 ks

  auto stageA = [&](int buf, int t) {
#pragma unroll
    for (int ld = 0; ld < 2; ++ld) {
      const int r = ld * 64 + wv * 8 + sr8;
      const int sl = ss ^ (r & 7);
      gl_lds16(A + (am0 + r) * KTOT + t * 64 + sl * 8, &lsA[buf][(ld * 64 + wv * 8) * 64]);
    }
  };
  auto stageB = [&](int buf, int t, int bp) {
#pragma unroll
    for (int ld = 0; ld < 2; ++ld) {
      const int r = bp * 128 + ld * 64 + wv * 8 + sr8;
      const int sl = ss ^ (r & 7);
      gl_lds16(Bm + (bn0 + r) * KTOT + t * 64 + sl * 8,
               &lsB[buf][(bp * 128 + ld * 64 + wv * 8) * 64]);
    }
  };

  // prologue: all chunks of tile 0, full drain
  stageA(0, 0);
#pragma unroll
  for (int bp = 0; bp < NBP; ++bp) stageB(0, 0, bp);
  waitvm<0>();
  __builtin_amdgcn_s_barrier();

#pragma unroll 2
  for (int t = 0; t < NT; ++t) {
    const int cur = t & 1;
    const bool pre = (t + 1 < NT);

#pragma unroll
    for (int bp = 0; bp < NBP; ++bp) {
      // ---- ds-reads for this phase (buf[cur], guaranteed by previous phase's vmcnt+barrier)
      if (bp == 0) {
#pragma unroll
        for (int i = 0; i < 4; ++i)
#pragma unroll
          for (int ks = 0; ks < 2; ++ks) {
            const int row = (wm + 2 * i) * 16 + fr;
            const int sl = (ks * 4 + kq) ^ (row & 7);
            af[i * 2 + ks] = *(const bf16x8*)((const char*)&lsA[cur][0] + row * 128 + sl * 16);
          }
      }
#pragma unroll
      for (int jj = 0; jj < 2; ++jj)
#pragma unroll
        for (int ks = 0; ks < 2; ++ks) {
          const int row = (wn + 4 * (2 * bp + jj)) * 16 + fr;
          const int sl = (ks * 4 + kq) ^ (row & 7);
          bq[jj * 2 + ks] = *(const bf16x8*)((const char*)&lsB[cur][0] + row * 128 + sl * 16);
        }

      // ---- stage one chunk of tile t+1; counted vmcnt (never 0 in steady loop)
      // steady: chunk staged at ph p (t) is vmcnt-forced complete by barrier ph (p-1) (t+1),
      //         i.e. >=2 phases in flight for NBP=3. Tail drains re-derived explicitly.
      if (pre) {
        if (bp == 0) {
          stageA(cur ^ 1, t + 1);
          stageB(cur ^ 1, t + 1, 0);
          waitvm<2 * NBP>();
        } else if (bp == NBP - 1) {
          stageB(cur ^ 1, t + 1, bp);
          waitvm<2 * (NBP - 1)>();
        } else {
          stageB(cur ^ 1, t + 1, bp);
          waitvm<2 * NBP>();
        }
      } else {
        if (bp == 0) waitvm<(NBP > 2) ? 2 : 0>();
        else waitvm<0>();
      }
      __builtin_amdgcn_s_barrier();

      // ---- MFMA quad for this phase
      __builtin_amdgcn_s_setprio(1);
#pragma unroll
      for (int i = 0; i < 4; ++i)
#pragma unroll
        for (int jj = 0; jj < 2; ++jj)
#pragma unroll
          for (int ks = 0; ks < 2; ++ks)
            acc[i][2 * bp + jj] = __builtin_amdgcn_mfma_f32_16x16x32_bf16(
                af[i * 2 + ks], bq[jj * 2 + ks], acc[i][2 * bp + jj], 0, 0, 0);
      __builtin_amdgcn_s_setprio(0);
    }
  }

  // epilogue
#pragma unroll
  for (int i = 0; i < 4; ++i) {
    const long row0 = am0 + (wm + 2 * i) * 16 + kq * 4;
#pragma unroll
    for (int j = 0; j < 2 * NBP; ++j) {
      const long col = bn0 + (wn + 4 * j) * 16 + fr;
      const float bv = bias ? bias[col] : 0.f;
#pragma unroll
      for (int q = 0; q < 4; ++q) {
        const float v = acc[i][j][q] + bv;
        if (OUT_BF16) ((bf16*)Cv)[(row0 + q) * Nn + col] = f2bf(v);
        else          ((float*)Cv)[(row0 + q) * Nn + col] = v;
      }
    }
  }
}

// ---------------- RoPE + head reshape ----------------
__global__ void rope_reshape(const bf16* __restrict__ qkv, const float* __restrict__ ct,
                             const float* __restrict__ st, bf16* __restrict__ q_r,
                             bf16* __restrict__ k_r) {
  long idx = (long)blockIdx.x * 256 + threadIdx.x;
  int j = idx & 63;
  int h = (idx >> 6) & 15;
  int n = (idx >> 10) & 2047;
  int b = (int)(idx >> 21);
  long row = (long)b * SEQ + n;
  float c = ct[n * 64 + j], s = st[n * 64 + j];
  long qoff = row * EQ + h * 128 + j;
  float q1 = bf2f(qkv[qoff]),        q2 = bf2f(qkv[qoff + 64]);
  float k1 = bf2f(qkv[qoff + 2048]), k2 = bf2f(qkv[qoff + 2048 + 64]);
  long obase = ((long)(b * 16 + h) * SEQ + n) * HD + j;
  q_r[obase]      = f2bf((q1 * c - q2 * s) * QSCALE_L2E);
  q_r[obase + 64] = f2bf((q1 * s + q2 * c) * QSCALE_L2E);
  k_r[obase]      = f2bf(k1 * c - k2 * s);
  k_r[obase + 64] = f2bf(k1 * s + k2 * c);
}

// ---------------- V transpose: qkv v-part -> v_t [bh, d(128), n(2048)] ----------------
__global__ __launch_bounds__(256) void v_transpose(const bf16* __restrict__ qkv,
                                                   bf16* __restrict__ v_t) {
  __shared__ bf16 tile[64][65];
  int bh = blockIdx.z;
  int b = bh >> 4, h = bh & 15;
  int n0 = blockIdx.y * 64, d0 = blockIdx.x * 64;
  int t = threadIdx.x;
#pragma unroll
  for (int p = 0; p < 16; ++p) {
    int e = p * 256 + t;
    int dn = e & 63, nn = e >> 6;
    tile[nn][dn] = qkv[(long)(b * SEQ + n0 + nn) * EQ + 2 * DM + h * 128 + d0 + dn];
  }
  __syncthreads();
#pragma unroll
  for (int p = 0; p < 16; ++p) {
    int e = p * 256 + t;
    int nn = e & 63, dd = e >> 6;
    v_t[((long)bh * HD + d0 + dd) * SEQ + n0 + nn] = tile[nn][dd];
  }
}

// ---------------- Flash attention, swapped-QK^T 32x32 structure ----------------
__global__ __launch_bounds__(256, 2) void attn_fwd(const bf16* __restrict__ q_r,
                                                   const bf16* __restrict__ k_r,
                                                   const bf16* __restrict__ v_t,
                                                   bf16* __restrict__ ao) {
  __shared__ alignas(16) char lds[65536];

  const int flat = blockIdx.y * gridDim.x + blockIdx.x;   // 0..511
  const int bh = (flat & 7) * 4 + ((flat >> 3) >> 4);
  const int qt = (flat >> 3) & 15;
  const int b = bh >> 4, h = bh & 15;

  const int wv = threadIdx.x >> 6, ln = threadIdx.x & 63;
  const int lh = ln >> 5;
  const int lq = ln & 31;
  const int q0 = qt * 128 + wv * 32;

  bf16x8 aq[8];
  {
    const char* qbase = (const char*)(q_r + ((long)bh * SEQ + q0 + lq) * HD);
#pragma unroll
    for (int ks = 0; ks < 8; ++ks)
      aq[ks] = *(const bf16x8*)(qbase + ks * 32 + lh * 16);
  }

  f32x16 oacc[4] = {};
  float mrow = -1e30f, lsum = 0.f;

  auto stage = [&](int buf, int t) {
    char* kb = lds + buf * 16384;
    char* vb = lds + 32768 + buf * 16384;
#pragma unroll
    for (int cc = 0; cc < 8; ++cc) {
      const int chunk = wv * 8 + cc;
      if (chunk < 16) {
        const int r = chunk * 4 + (ln >> 4);
        const char* src = (const char*)k_r + ((long)bh * SEQ + t * 64 + r) * 256 +
                          (((ln & 15) ^ (r & 15)) << 4);
        gl_lds16(src, kb + chunk * 1024);
      } else {
        const int c2 = chunk - 16;
        const int r = c2 * 8 + (ln >> 3);
        const char* src = (const char*)v_t + ((long)bh * HD + r) * (SEQ * 2) + t * 128 +
                          (((ln & 7) ^ (r & 7)) << 4);
        gl_lds16(src, vb + c2 * 1024);
      }
    }
  };

  stage(0, 0);
  __syncthreads();

  for (int t = 0; t < SEQ / 64; ++t) {
    const int cur = t & 1;
    if (t + 1 < SEQ / 64) stage(cur ^ 1, t + 1);
    const char* kb = lds + cur * 16384;
    const char* vb = lds + 32768 + cur * 16384;

    f32x16 sacc[2] = {};
    __builtin_amdgcn_s_setprio(1);
#pragma unroll
    for (int kvs = 0; kvs < 2; ++kvs) {
      const int kv = kvs * 32 + lq;
#pragma unroll
      for (int ks = 0; ks < 8; ++ks) {
        bf16x8 kf = *(const bf16x8*)(kb + kv * 256 + ((((ks << 1) | lh) ^ (kv & 15)) << 4));
        sacc[kvs] = __builtin_amdgcn_mfma_f32_32x32x16_bf16(kf, aq[ks], sacc[kvs], 0, 0, 0);
      }
    }
    __builtin_amdgcn_s_setprio(0);

    float mx = sacc[0][0];
#pragma unroll
    for (int r = 1; r < 16; ++r) mx = fmaxf(mx, sacc[0][r]);
#pragma unroll
    for (int r = 0; r < 16; ++r) mx = fmaxf(mx, sacc[1][r]);
    mx = fmaxf(mx, __shfl_xor(mx, 32, 64));
    const float mn = fmaxf(mrow, mx);
    const float scale = fexp2(mrow - mn);
    mrow = mn;
    float psum = 0.f;
#pragma unroll
    for (int k2 = 0; k2 < 2; ++k2)
#pragma unroll
      for (int r = 0; r < 16; ++r) {
        const float pv = fexp2(sacc[k2][r] - mn);
        sacc[k2][r] = pv;
        psum += pv;
      }
    psum += __shfl_xor(psum, 32, 64);
    lsum = lsum * scale + psum;
#pragma unroll
    for (int dt = 0; dt < 4; ++dt) oacc[dt] *= scale;

    bf16x8 pfrag[4];
#pragma unroll
    for (int k2 = 0; k2 < 2; ++k2) {
      unsigned int pk[8];
#pragma unroll
      for (int i = 0; i < 8; ++i) {
        unsigned int lo = __bfloat16_as_ushort(f2bf(sacc[k2][2 * i]));
        unsigned int hi = __bfloat16_as_ushort(f2bf(sacc[k2][2 * i + 1]));
        pk[i] = lo | (hi << 16);
      }
#pragma unroll
      for (int fb = 0; fb < 2; ++fb) {
        const unsigned int a0 = pk[fb * 4 + 0], a1 = pk[fb * 4 + 1];
        const unsigned int b0 = pk[fb * 4 + 2], b1 = pk[fb * 4 + 3];
        const unsigned int sb0 = __shfl_xor(b0, 32, 64);
        const unsigned int sb1 = __shfl_xor(b1, 32, 64);
        const unsigned int sa0 = __shfl_xor(a0, 32, 64);
        const unsigned int sa1 = __shfl_xor(a1, 32, 64);
        u32x4 wvec;
        wvec.x = lh ? sb0 : a0;
        wvec.y = lh ? sb1 : a1;
        wvec.z = lh ? b0 : sa0;
        wvec.w = lh ? b1 : sa1;
        pfrag[k2 * 2 + fb] = __builtin_bit_cast(bf16x8, wvec);
      }
    }

    __builtin_amdgcn_s_setprio(1);
#pragma unroll
    for (int dt = 0; dt < 4; ++dt) {
      const int d = dt * 32 + lq;
#pragma unroll
      for (int kk = 0; kk < 4; ++kk) {
        bf16x8 vf = *(const bf16x8*)(vb + d * 128 + ((((kk << 1) | lh) ^ (d & 7)) << 4));
        oacc[dt] = __builtin_amdgcn_mfma_f32_32x32x16_bf16(vf, pfrag[kk], oacc[dt], 0, 0, 0);
      }
    }
    __builtin_amdgcn_s_setprio(0);
    __syncthreads();
  }

  const float inv = 1.0f / lsum;
  bf16* ob = (bf16*)lds;
  const int qloc = wv * 32 + lq;
#pragma unroll
  for (int dt = 0; dt < 4; ++dt)
#pragma unroll
    for (int r = 0; r < 16; ++r) {
      const int d = dt * 32 + (r & 3) + 8 * (r >> 2) + 4 * lh;
      ob[qloc * 132 + d] = f2bf(oacc[dt][r] * inv);
    }
#pragma unroll
  for (int it = 0; it < 8; ++it) {
    const int c = it * 64 + ln;
    const int qq = c >> 4, dc = c & 15;
    const char* srcp = (const char*)ob + (wv * 32 + qq) * 264 + dc * 16;
    uint2 v0 = *(const uint2*)srcp;
    uint2 v1 = *(const uint2*)(srcp + 8);
    uint4 outv;
    outv.x = v0.x; outv.y = v0.y; outv.z = v1.x; outv.w = v1.y;
    *(uint4*)((char*)(ao + ((long)b * SEQ + qt * 128 + wv * 32 + qq) * DM + h * 128) + dc * 16) = outv;
  }
}

// ---------------- launch ----------------
extern "C" void kernel_launch(void* const* d_in, const int* in_sizes, int n_in,
                              void* d_out, int out_size, void* d_ws, size_t ws_size,
                              hipStream_t stream) {
  const float* x      = (const float*)d_in[0];
  const float* w_qkv  = (const float*)d_in[1];
  const float* w_proj = (const float*)d_in[2];
  const float* b_proj = (const float*)d_in[3];

  char* ws = (char*)d_ws;
  size_t off = 0;
  auto alloc = [&](size_t bytes) {
    void* p = ws + off;
    off += (bytes + 255) & ~(size_t)255;
    return p;
  };
  bf16* xb     = (bf16*)alloc((size_t)MROWS * DM * 2);
  bf16* wqkvb  = (bf16*)alloc((size_t)EQ * DM * 2);
  bf16* wprojb = (bf16*)alloc((size_t)DM * DM * 2);
  bf16* qkvb   = (bf16*)alloc((size_t)MROWS * EQ * 2);
  bf16* q_r    = (bf16*)alloc((size_t)Bz * H * SEQ * HD * 2);
  bf16* k_r    = (bf16*)alloc((size_t)Bz * H * SEQ * HD * 2);
  bf16* v_t    = (bf16*)alloc((size_t)Bz * H * SEQ * HD * 2);
  bf16* aob    = (bf16*)alloc((size_t)MROWS * DM * 2);
  float* ct    = (float*)alloc((size_t)SEQ * 64 * 4);
  float* st    = (float*)alloc((size_t)SEQ * 64 * 4);

  {
    long n = MROWS * DM;
    f32_to_bf16<<<(int)((n / 4 + 255) / 256), 256, 0, stream>>>(x, xb, n);
  }
  {
    long n = (long)EQ * DM;
    f32_to_bf16<<<(int)((n / 4 + 255) / 256), 256, 0, stream>>>(w_qkv, wqkvb, n);
  }
  {
    long n = (long)DM * DM;
    f32_to_bf16<<<(int)((n / 4 + 255) / 256), 256, 0, stream>>>(w_proj, wprojb, n);
  }
  rope_table<<<(SEQ * 64) / 256, 256, 0, stream>>>(ct, st);

  // GEMM1: 4096x6144x2048, BM=128 BN=384 -> grid 512 = 2 exact rounds
  gemm128<2048, 384, 3, 1><<<(int)(MROWS / 128) * (EQ / 384), 512, 0, stream>>>(
      xb, wqkvb, qkvb, nullptr, (int)MROWS, EQ);

  rope_reshape<<<(int)((long)Bz * SEQ * H * 64 / 256), 256, 0, stream>>>(qkvb, ct, st, q_r, k_r);
  v_transpose<<<dim3(HD / 64, SEQ / 64, Bz * H), 256, 0, stream>>>(qkvb, v_t);

  attn_fwd<<<dim3(16, Bz * H), 256, 0, stream>>>(q_r, k_r, v_t, aob);

  // GEMM2: 4096x2048x2048, BM=128 BN=256 -> grid 256 = 1 exact round
  gemm128<2048, 256, 2, 0><<<(int)(MROWS / 128) * (DM / 256), 512, 0, stream>>>(
      aob, wprojb, d_out, b_proj, (int)MROWS, DM);
}